// Round 12
// baseline (548.868 us; speedup 1.0000x reference)
//
#include <hip/hip_runtime.h>
#include <hip/hip_cooperative_groups.h>
#include <hip/hip_bf16.h>
#include <cfloat>
#include <cstdint>

namespace cg = cooperative_groups;

// ---------------------------------------------------------------------------
// GATv2 x3 + global max/mean pool + linear head.
// Round 11: dispatch-count attack. ~180 us of the 332 was unaccounted by
// kernel-time estimates => launch/gap overhead across 14 serial dispatches.
// build_k (cooperative): init + x/weight bf16 convert + histogram + 3-phase
// scan + scatter in ONE kernel (4 grid.sync's). tail_k (cooperative): pool +
// final. 14 -> 8 dispatches. fused_agg: 8-edge unrolled main loop for ILP.
// ---------------------------------------------------------------------------

typedef __attribute__((ext_vector_type(8))) short bf16x8;
typedef __attribute__((ext_vector_type(4))) float f32x4;
typedef __attribute__((ext_vector_type(2))) float v2f;
typedef __attribute__((ext_vector_type(4))) unsigned short us4;
typedef __attribute__((ext_vector_type(2))) unsigned short us2;

#define L2E 1.4426950408889634f

__device__ __forceinline__ float bf2f(unsigned short u) {
    return __uint_as_float((unsigned)u << 16);
}
__device__ __forceinline__ unsigned short f2bf(float f) {   // RNE
    unsigned u = __float_as_uint(f);
    u += 0x7FFFu + ((u >> 16) & 1u);
    return (unsigned short)(u >> 16);
}
__device__ __forceinline__ v2f unpack2(unsigned d) {        // [lo,hi] bf16 -> f32
    v2f r;
    r.x = __uint_as_float(d << 16);
    r.y = __uint_as_float(d & 0xffff0000u);
    return r;
}
__device__ __forceinline__ unsigned pack2(float a, float b) {
    return (unsigned)f2bf(a) | ((unsigned)f2bf(b) << 16);
}

// ---- cross-lane sum helpers -------------------------------------------------
template<int CTRL>
__device__ __forceinline__ float dpp_add_f(float x) {
    int xi = __float_as_int(x);
    int yi = __builtin_amdgcn_update_dpp(xi, xi, CTRL, 0xF, 0xF, false);
    return x + __int_as_float(yi);
}
template<int PAT>
__device__ __forceinline__ float swz_add_f(float x) {
    int yi = __builtin_amdgcn_ds_swizzle(__float_as_int(x), PAT);
    return x + __int_as_float(yi);
}
template<int GS>
__device__ __forceinline__ float group_sum(float p) {
    p = dpp_add_f<0x121>(p);   // row_ror:1
    p = dpp_add_f<0x122>(p);   // row_ror:2
    p = dpp_add_f<0x124>(p);   // row_ror:4
    p = dpp_add_f<0x128>(p);   // row_ror:8
    if constexpr (GS >= 32) p = swz_add_f<0x401F>(p);   // xor 16
    if constexpr (GS >= 64) p += __shfl_xor(p, 32, 64); // cross-half
    return p;
}

// ---------------------------------------------------------------------------
// build_k (cooperative, grid 256x256): phase0 zero deg + pool-buf init +
// x/weights -> bf16; phase1 dst histogram; phase2 per-tile scan; phase3
// cross-tile offsets; phase4 scatter.
// ---------------------------------------------------------------------------
struct BuildArgs {
    const float* x; unsigned short* xb; int nx;
    const float* w0; const float* w1; const float* w2;
    const float* w3; const float* w4; const float* w5;
    unsigned short* d0; unsigned short* d1; unsigned short* d2;
    unsigned short* d3; unsigned short* d4; unsigned short* d5;
    int s01, s23, s45;
    const int* src; const int* dst; int E; int N;
    int* deg; int* rowptr; int* bsum; int* esrc;
    float* gsum; float* gcnt; unsigned* gmaxu; int G;
};

__global__ __launch_bounds__(256) void build_k(BuildArgs a)
{
    cg::grid_group grid = cg::this_grid();
    const int tid = blockIdx.x * blockDim.x + threadIdx.x;
    const int gsz = gridDim.x * blockDim.x;

    // ---- phase 0: zero/init + conversions
    for (int k = tid; k < a.N; k += gsz) a.deg[k] = 0;
    for (int k = tid; k < a.G * 64; k += gsz) { a.gsum[k] = 0.f; a.gmaxu[k] = 0x00800000u; }
    for (int k = tid; k < a.G; k += gsz) a.gcnt[k] = 0.f;
    for (int i = tid; i < a.nx / 4; i += gsz) {
        int idx = i * 4;
        float4 v = *(const float4*)(a.x + idx);
        uint2 o = { pack2(v.x, v.y), pack2(v.z, v.w) };
        *(uint2*)(a.xb + idx) = o;
    }
    {
        const int wtot4 = (2 * a.s01 + 2 * a.s23 + 2 * a.s45) / 4;
        const int t0 = 2 * a.s01, t1 = t0 + 2 * a.s23;
        for (int i = tid; i < wtot4; i += gsz) {
            int e = i * 4;
            const float* s; unsigned short* d; int off;
            if (e < t0)      { int j = e;      s = (j < a.s01) ? a.w0 : a.w1; d = (j < a.s01) ? a.d0 : a.d1; off = j % a.s01; }
            else if (e < t1) { int j = e - t0; s = (j < a.s23) ? a.w2 : a.w3; d = (j < a.s23) ? a.d2 : a.d3; off = j % a.s23; }
            else             { int j = e - t1; s = (j < a.s45) ? a.w4 : a.w5; d = (j < a.s45) ? a.d4 : a.d5; off = j % a.s45; }
            float4 v = *(const float4*)(s + off);
            uint2 o = { pack2(v.x, v.y), pack2(v.z, v.w) };
            *(uint2*)((unsigned short*)d + off) = o;
        }
    }
    grid.sync();

    // ---- phase 1: histogram (self loops included)
    for (int e = tid; e < a.E + a.N; e += gsz) {
        int i = (e < a.E) ? a.dst[e] : (e - a.E);
        atomicAdd(&a.deg[i], 1);
    }
    grid.sync();

    // ---- phase 2: per-tile inclusive scan (tile = 8192, 32 elems/thread)
    const int nblk = (a.N + 8191) / 8192;
    __shared__ int parts[4];
    __shared__ int ptot;
    if ((int)blockIdx.x < nblk) {
        const int t = threadIdx.x, lane = t & 63, wv = t >> 6;
        const int base = blockIdx.x * 8192;
        int v[32];
        int run = 0;
        #pragma unroll
        for (int i = 0; i < 32; ++i) {
            int idx = base + t * 32 + i;
            run += (idx < a.N) ? a.deg[idx] : 0;
            v[i] = run;
        }
        int x = run;
        #pragma unroll
        for (int off = 1; off < 64; off <<= 1) {
            int y = __shfl_up(x, off, 64);
            if (lane >= off) x += y;
        }
        int excl = x - run;
        if (lane == 63) parts[wv] = x;
        __syncthreads();
        if (t == 0) {
            int acc2 = 0;
            #pragma unroll
            for (int w2 = 0; w2 < 4; ++w2) { int tmp = parts[w2]; parts[w2] = acc2; acc2 += tmp; }
            ptot = acc2;
        }
        __syncthreads();
        int pre = parts[wv] + excl;
        #pragma unroll
        for (int i = 0; i < 32; ++i) {
            int idx = base + t * 32 + i;
            if (idx < a.N) a.rowptr[idx + 1] = pre + v[i];
        }
        if (t == 0) a.bsum[blockIdx.x] = ptot;
    }
    grid.sync();

    // ---- phase 3: cross-tile offsets
    if ((int)blockIdx.x < nblk && blockIdx.x > 0) {
        int off3 = 0;
        for (int i = 0; i < (int)blockIdx.x; ++i) off3 += a.bsum[i];
        const int base = blockIdx.x * 8192;
        for (int i = threadIdx.x; i < 8192; i += 256) {
            int idx = base + i;
            if (idx < a.N) a.rowptr[idx + 1] += off3;
        }
    }
    if (tid == 0) a.rowptr[0] = 0;
    grid.sync();

    // ---- phase 4: scatter (deg consumed by countdown)
    for (int e = tid; e < a.E + a.N; e += gsz) {
        int i = (e < a.E) ? a.dst[e] : (e - a.E);
        int j = (e < a.E) ? a.src[e] : (e - a.E);
        int old = atomicAdd(&a.deg[i], -1);
        a.esrc[a.rowptr[i] + old - 1] = j;
    }
}

// ---------------------------------------------------------------------------
// LDS-staged bf16 MFMA GEMM (round-10, unchanged).
// ---------------------------------------------------------------------------
template<int K, int SLAB>
__global__ __launch_bounds__(256) void gemm_lds(
    const unsigned short* __restrict__ A,
    const unsigned short* __restrict__ Wl, const unsigned short* __restrict__ Wr,
    unsigned short* __restrict__ Cl, unsigned short* __restrict__ Cr,
    int M, int Nout)
{
    constexpr int KC   = 128;
    constexpr int WPAD = KC + 8;
    constexpr int NT   = SLAB / 32;
    __shared__ unsigned short Ws[SLAB * WPAD];

    const int tid = threadIdx.x, wv = tid >> 6, lane = tid & 63;
    const int r16 = lane & 15, quad = lane >> 4;
    const int m0 = blockIdx.x * 64;
    const int mh = (wv >> 1) * 32;
    const int nh = (wv & 1) * (SLAB / 2);
    const int ncol0 = blockIdx.y * SLAB;

    f32x4 acc[2][2][NT] = {};

    const unsigned short* Arow[2];
    #pragma unroll
    for (int mt = 0; mt < 2; ++mt) {
        int r = m0 + mh + mt * 16 + r16;
        r = (r < M) ? r : (M - 1);
        Arow[mt] = A + (size_t)r * K + quad * 8;
    }

    for (int kc = 0; kc < K / KC; ++kc) {
        const int k0 = kc * KC;
        bf16x8 a[2][4];
        #pragma unroll
        for (int mt = 0; mt < 2; ++mt)
            #pragma unroll
            for (int ks = 0; ks < 4; ++ks)
                a[mt][ks] = *(const bf16x8*)(Arow[mt] + k0 + ks * 32);

        #pragma unroll
        for (int side = 0; side < 2; ++side) {
            const unsigned short* W = side ? Wr : Wl;
            __syncthreads();
            #pragma unroll
            for (int it = 0; it < SLAB * KC / 2048; ++it) {
                int idx8 = (it * 256 + tid) * 8;
                int row = idx8 >> 7, col = idx8 & 127;
                bf16x8 v = *(const bf16x8*)(W + (size_t)(ncol0 + row) * K + k0 + col);
                *(bf16x8*)(&Ws[row * WPAD + col]) = v;
            }
            __syncthreads();
            #pragma unroll
            for (int ks = 0; ks < 4; ++ks) {
                #pragma unroll
                for (int n = 0; n < NT; ++n) {
                    bf16x8 b = *(const bf16x8*)(&Ws[(nh + n * 16 + r16) * WPAD + ks * 32 + quad * 8]);
                    #pragma unroll
                    for (int mt = 0; mt < 2; ++mt)
                        acc[side][mt][n] = __builtin_amdgcn_mfma_f32_16x16x32_bf16(
                            a[mt][ks], b, acc[side][mt][n], 0, 0, 0);
                }
            }
        }
    }

    constexpr int RP  = SLAB / 2 + 8;
    constexpr int LPR = SLAB / 16;
    constexpr int RPI = 64 / LPR;
    const int il = lane % LPR, rr = lane / LPR;
    #pragma unroll
    for (int side = 0; side < 2; ++side) {
        unsigned short* C = side ? Cr : Cl;
        __syncthreads();
        unsigned short* L = &Ws[wv * 32 * RP];
        #pragma unroll
        for (int mt = 0; mt < 2; ++mt)
            #pragma unroll
            for (int n = 0; n < NT; ++n)
                #pragma unroll
                for (int r = 0; r < 4; ++r)
                    L[(mt * 16 + quad * 4 + r) * RP + n * 16 + r16] = f2bf(acc[side][mt][n][r]);
        #pragma unroll
        for (int t = 0; t < 32 / RPI; ++t) {
            int row = t * RPI + rr;
            uint4 v = *(const uint4*)(&L[row * RP + il * 8]);
            int gr = m0 + mh + row;
            if (gr < M)
                *(uint4*)(C + (size_t)gr * Nout + ncol0 + nh + il * 8) = v;
        }
    }
}

// ---------------------------------------------------------------------------
// Fused GATv2 layer: U-edge generic processor, 8/4/1 unroll ladder.
// ---------------------------------------------------------------------------
template<int P>
__device__ __forceinline__ float edge_logit(const v2f* xv, const v2f* xrv, const v2f* attv)
{
    v2f d = {0.f, 0.f};
    #pragma unroll
    for (int p = 0; p < P; ++p) {
        v2f z = xv[p] + xrv[p];
        v2f l = __builtin_elementwise_max(z, z * 0.2f);
        d += l * attv[p];
    }
    return d.x + d.y;
}

template<int P>
__device__ __forceinline__ void load_edge(const unsigned short* __restrict__ xl,
                                          size_t base, v2f* xv)
{
    if constexpr (P == 2) {
        uint2 a = *(const uint2*)(xl + base);
        xv[0] = unpack2(a.x); xv[1] = unpack2(a.y);
    } else {
        unsigned a = *(const unsigned*)(xl + base);
        xv[0] = unpack2(a);
    }
}

template<int U, int H>
__device__ __forceinline__ void do_edges(
    const unsigned short* __restrict__ xl, const int* __restrict__ esrc,
    int k, int f0, const v2f* xrv, const v2f* attv, float& s, v2f* acc)
{
    constexpr int P  = H / 2;
    constexpr int HD = H * 64;
    constexpr int GS = 64 / H;
    int j[U];
    #pragma unroll
    for (int i = 0; i < U; ++i) j[i] = esrc[k + i];
    v2f xv[U][P];
    #pragma unroll
    for (int i = 0; i < U; ++i)
        load_edge<P>(xl, (size_t)j[i] * HD + f0, xv[i]);
    float pl[U];
    #pragma unroll
    for (int i = 0; i < U; ++i) pl[i] = edge_logit<P>(xv[i], xrv, attv);
    #pragma unroll
    for (int i = 0; i < U; ++i) pl[i] = group_sum<GS>(pl[i]);
    float w[U];
    #pragma unroll
    for (int i = 0; i < U; ++i) w[i] = __builtin_amdgcn_exp2f(pl[i]);
    #pragma unroll
    for (int i = 0; i < U; ++i) s += w[i];
    #pragma unroll
    for (int p = 0; p < P; ++p) {
        v2f t = {0.f, 0.f};
        #pragma unroll
        for (int i = 0; i < U; ++i) t += xv[i][p] * w[i];
        acc[p] += t;
    }
}

template<int H, bool BF16OUT>
__global__ __launch_bounds__(256) void fused_agg_k(
    const unsigned short* __restrict__ xl, const unsigned short* __restrict__ xr,
    const int* __restrict__ rowptr, const int* __restrict__ esrc,
    const float* __restrict__ att, const float* __restrict__ bias,
    void* __restrict__ outv, int N, float oslope)
{
    const int wid  = __builtin_amdgcn_readfirstlane(
                         (blockIdx.x * blockDim.x + threadIdx.x) >> 6);
    const int lane = threadIdx.x & 63;
    if (wid >= N) return;
    constexpr int HD = H * 64;
    const int f0 = lane * H;
    const int r0 = rowptr[wid];
    const int r1 = rowptr[wid + 1];

    if constexpr (H >= 2) {
        constexpr int P = H / 2;
        v2f xrv[P], attv[P], acc[P];
        load_edge<P>(xr, (size_t)wid * HD + f0, xrv);
        #pragma unroll
        for (int p = 0; p < P; ++p) {
            attv[p] = *(const v2f*)(att + f0 + 2 * p) * L2E;
            acc[p] = (v2f){0.f, 0.f};
        }

        float s = 0.f;
        int k = r0;
        for (; k + 8 <= r1; k += 8) do_edges<8, H>(xl, esrc, k, f0, xrv, attv, s, acc);
        for (; k + 4 <= r1; k += 4) do_edges<4, H>(xl, esrc, k, f0, xrv, attv, s, acc);
        for (; k < r1; ++k)         do_edges<1, H>(xl, esrc, k, f0, xrv, attv, s, acc);

        float rs = 1.f / (s + 1e-16f);
        unsigned short o[H];
        float of[H];
        #pragma unroll
        for (int p = 0; p < P; ++p) {
            v2f b2 = *(const v2f*)(bias + f0 + 2 * p);
            v2f v = acc[p] * rs + b2;
            v = __builtin_elementwise_max(v, v * oslope);
            if constexpr (BF16OUT) { o[2 * p] = f2bf(v.x); o[2 * p + 1] = f2bf(v.y); }
            else                   { of[2 * p] = v.x; of[2 * p + 1] = v.y; }
        }
        if constexpr (BF16OUT) {
            unsigned short* ou = (unsigned short*)outv;
            if constexpr (H == 4) *(us4*)(ou + (size_t)wid * HD + f0) = *(us4*)o;
            else                  *(us2*)(ou + (size_t)wid * HD + f0) = *(us2*)o;
        } else {
            float* off_ = (float*)outv;
            #pragma unroll
            for (int i = 0; i < H; ++i) off_[(size_t)wid * HD + f0 + i] = of[i];
        }
    } else {
        // H == 1: scalar feats, GS = 64
        float xrv  = bf2f(xr[(size_t)wid * 64 + lane]);
        float attv = att[lane] * L2E;
        float s = 0.f, acc = 0.f;
        int k = r0;
        for (; k + 4 <= r1; k += 4) {
            int j[4];
            #pragma unroll
            for (int i = 0; i < 4; ++i) j[i] = esrc[k + i];
            float xv[4], pl[4], w[4];
            #pragma unroll
            for (int i = 0; i < 4; ++i) xv[i] = bf2f(xl[(size_t)j[i] * 64 + lane]);
            #pragma unroll
            for (int i = 0; i < 4; ++i) {
                float z = xv[i] + xrv;
                pl[i] = fmaxf(z, 0.2f * z) * attv;
            }
            #pragma unroll
            for (int i = 0; i < 4; ++i) pl[i] = group_sum<64>(pl[i]);
            #pragma unroll
            for (int i = 0; i < 4; ++i) w[i] = __builtin_amdgcn_exp2f(pl[i]);
            s += (w[0] + w[1]) + (w[2] + w[3]);
            acc += (xv[0] * w[0] + xv[1] * w[1]) + (xv[2] * w[2] + xv[3] * w[3]);
        }
        for (; k < r1; ++k) {
            float x0 = bf2f(xl[(size_t)esrc[k] * 64 + lane]);
            float z = x0 + xrv;
            float pl = group_sum<64>(fmaxf(z, 0.2f * z) * attv);
            float w = __builtin_amdgcn_exp2f(pl);
            s += w;
            acc += x0 * w;
        }
        float rs = 1.f / (s + 1e-16f);
        float v = acc * rs + bias[lane];
        v = fmaxf(v, oslope * v);
        if constexpr (BF16OUT)
            ((unsigned short*)outv)[(size_t)wid * 64 + lane] = f2bf(v);
        else
            ((float*)outv)[(size_t)wid * 64 + lane] = v;
    }
}

// ---------------------------------------------------------------------------
// tail_k (cooperative, grid 256x256): pool (run aggregation over sorted
// batch_index, grid-stride) + grid.sync + final head.
// ---------------------------------------------------------------------------
__device__ __forceinline__ unsigned fenc(float f) {
    unsigned u = __float_as_uint(f);
    return (u & 0x80000000u) ? ~u : (u | 0x80000000u);
}
__device__ __forceinline__ float fdec(unsigned u) {
    return __uint_as_float((u & 0x80000000u) ? (u & 0x7fffffffu) : ~u);
}

struct TailArgs {
    const float* h3; const int* batch; int N;
    unsigned* gmaxu; float* gsum; float* gcnt;
    const float* outw; const float* outb;
    float* out; float* hid_out; int G;
};

__global__ __launch_bounds__(256) void tail_k(TailArgs a)
{
    cg::grid_group grid = cg::this_grid();
    const int wv = threadIdx.x >> 6, lane = threadIdx.x & 63;

    // ---- pool phase
    const int nchunks = (a.N + 15) / 16;
    for (int c = blockIdx.x * 4 + wv; c < nchunks; c += gridDim.x * 4) {
        const int n0 = c * 16;
        int gcur = a.batch[n0];
        float vmax = -3.4e38f, vsum = 0.f;
        int cnt = 0;
        for (int i = 0; i < 16; ++i) {
            int n = n0 + i;
            if (n >= a.N) break;
            int g = a.batch[n];
            if (g != gcur) {
                atomicMax(&a.gmaxu[gcur * 64 + lane], fenc(vmax));
                atomicAdd(&a.gsum[gcur * 64 + lane], vsum);
                if (lane == 0) atomicAdd(&a.gcnt[gcur], (float)cnt);
                gcur = g; vmax = -3.4e38f; vsum = 0.f; cnt = 0;
            }
            float v = a.h3[(size_t)n * 64 + lane];
            vmax = fmaxf(vmax, v);
            vsum += v;
            cnt++;
        }
        atomicMax(&a.gmaxu[gcur * 64 + lane], fenc(vmax));
        atomicAdd(&a.gsum[gcur * 64 + lane], vsum);
        if (lane == 0) atomicAdd(&a.gcnt[gcur], (float)cnt);
    }
    grid.sync();

    // ---- final head: block g handles graph g (grid == G)
    const int g = blockIdx.x;
    const int t = threadIdx.x;
    __shared__ float hid[128];
    if (g < a.G) {
        if (t < 128) {
            float v;
            if (t < 64) v = fdec(a.gmaxu[g * 64 + t]);
            else {
                float c = fmaxf(a.gcnt[g], 1.f);
                v = a.gsum[g * 64 + (t - 64)] / c;
            }
            hid[t] = v;
            a.hid_out[(size_t)g * 128 + t] = v;
        }
        __syncthreads();
        if (t < 128) {
            const int w = t >> 6, ln = t & 63;
            float p = hid[ln] * a.outw[w * 128 + ln] + hid[ln + 64] * a.outw[w * 128 + 64 + ln];
            #pragma unroll
            for (int off = 32; off >= 1; off >>= 1) p += __shfl_xor(p, off, 64);
            if (ln == 0) a.out[g * 2 + w] = p + a.outb[w];
        }
    }
}

// ---------------------------------------------------------------------------
extern "C" void kernel_launch(void* const* d_in, const int* in_sizes, int n_in,
                              void* d_out, int out_size, void* d_ws, size_t ws_size,
                              hipStream_t stream)
{
    const float* x    = (const float*)d_in[0];
    const int*   ei   = (const int*)d_in[1];
    const int*   batch= (const int*)d_in[2];
    const float* w1l  = (const float*)d_in[3];
    const float* w1r  = (const float*)d_in[4];
    const float* att1 = (const float*)d_in[5];
    const float* b1   = (const float*)d_in[6];
    const float* w2l  = (const float*)d_in[7];
    const float* w2r  = (const float*)d_in[8];
    const float* att2 = (const float*)d_in[9];
    const float* b2   = (const float*)d_in[10];
    const float* w3l  = (const float*)d_in[11];
    const float* w3r  = (const float*)d_in[12];
    const float* att3 = (const float*)d_in[13];
    const float* b3   = (const float*)d_in[14];
    const float* outw = (const float*)d_in[15];
    const float* outb = (const float*)d_in[16];

    const int N   = in_sizes[2];
    const int E   = in_sizes[1] / 2;
    const int E2  = E + N;
    const int G   = 256;
    const int FIN = in_sizes[0] / N;    // 128
    const int* src = ei;
    const int* dst = ei + E;

    char* ws = (char*)d_ws;
    size_t off = 0;
    auto alloc = [&](size_t bytes) -> void* {
        void* p = ws + off;
        off = (off + bytes + 255) & ~(size_t)255;
        return p;
    };
    unsigned short* xlb   = (unsigned short*)alloc((size_t)N * 256 * 2);
    unsigned short* xrb   = (unsigned short*)alloc((size_t)N * 256 * 2);
    unsigned short* xb    = (unsigned short*)alloc((size_t)N * 128 * 2);
    unsigned short* hAb   = (unsigned short*)alloc((size_t)N * 256 * 2);
    unsigned short* hBb   = (unsigned short*)alloc((size_t)N * 128 * 2);
    float*          h3    = (float*)alloc((size_t)N * 64 * 4);
    int*            rowptr= (int*)alloc((size_t)(N + 1) * 4);
    int*            deg   = (int*)alloc((size_t)N * 4);
    int*            esrc  = (int*)alloc((size_t)E2 * 4);
    int*            bsum  = (int*)alloc(64 * 4);
    unsigned*       gmaxu = (unsigned*)alloc((size_t)G * 64 * 4);
    float*          gsum  = (float*)alloc((size_t)G * 64 * 4);
    float*          gcnt  = (float*)alloc((size_t)G * 4);
    unsigned short* w1lb  = (unsigned short*)alloc(256 * 128 * 2);
    unsigned short* w1rb  = (unsigned short*)alloc(256 * 128 * 2);
    unsigned short* w2lb  = (unsigned short*)alloc(128 * 256 * 2);
    unsigned short* w2rb  = (unsigned short*)alloc(128 * 256 * 2);
    unsigned short* w3lb  = (unsigned short*)alloc(64 * 128 * 2);
    unsigned short* w3rb  = (unsigned short*)alloc(64 * 128 * 2);

    // ---- build: init + convert + histogram + scan + scatter (cooperative)
    BuildArgs ba;
    ba.x = x; ba.xb = xb; ba.nx = N * FIN;
    ba.w0 = w1l; ba.w1 = w1r; ba.w2 = w2l; ba.w3 = w2r; ba.w4 = w3l; ba.w5 = w3r;
    ba.d0 = w1lb; ba.d1 = w1rb; ba.d2 = w2lb; ba.d3 = w2rb; ba.d4 = w3lb; ba.d5 = w3rb;
    ba.s01 = 256 * 128; ba.s23 = 128 * 256; ba.s45 = 64 * 128;
    ba.src = src; ba.dst = dst; ba.E = E; ba.N = N;
    ba.deg = deg; ba.rowptr = rowptr; ba.bsum = bsum; ba.esrc = esrc;
    ba.gsum = gsum; ba.gcnt = gcnt; ba.gmaxu = gmaxu; ba.G = G;
    void* bargs[] = { &ba };
    hipLaunchCooperativeKernel((void*)build_k, dim3(256), dim3(256), bargs, 0, stream);

    const int gx  = (N + 63) / 64;           // 64-row GEMM blocks
    const int nwb = (N * 64 + 255) / 256;    // one wave per node

    // ---- layer 1: K=128 -> H=4, HD=256 (SLAB=128, 2 col-blocks)
    gemm_lds<128, 128><<<dim3(gx, 2), 256, 0, stream>>>(
        xb, w1lb, w1rb, xlb, xrb, N, 256);
    fused_agg_k<4, true><<<nwb, 256, 0, stream>>>(xlb, xrb, rowptr, esrc, att1, b1, hAb, N, 0.01f);

    // ---- layer 2: K=256 -> H=2, HD=128 (SLAB=128)
    gemm_lds<256, 128><<<dim3(gx, 1), 256, 0, stream>>>(
        hAb, w2lb, w2rb, xlb, xrb, N, 128);
    fused_agg_k<2, true><<<nwb, 256, 0, stream>>>(xlb, xrb, rowptr, esrc, att2, b2, hBb, N, 0.01f);

    // ---- layer 3: K=128 -> H=1, HD=64 (SLAB=64)
    gemm_lds<128, 64><<<dim3(gx, 1), 256, 0, stream>>>(
        hBb, w3lb, w3rb, xlb, xrb, N, 64);
    fused_agg_k<1, false><<<nwb, 256, 0, stream>>>(xlb, xrb, rowptr, esrc, att3, b3, h3, N, 0.01f);

    // ---- pooling + head (cooperative)
    TailArgs ta;
    ta.h3 = h3; ta.batch = batch; ta.N = N;
    ta.gmaxu = gmaxu; ta.gsum = gsum; ta.gcnt = gcnt;
    ta.outw = outw; ta.outb = outb;
    ta.out = (float*)d_out; ta.hid_out = (float*)d_out + G * 2; ta.G = G;
    void* targs[] = { &ta };
    hipLaunchCooperativeKernel((void*)tail_k, dim3(256), dim3(256), targs, 0, stream);
}

// Round 13
// 337.847 us; speedup vs baseline: 1.6246x; 1.6246x over previous
//
#include <hip/hip_runtime.h>
#include <hip/hip_bf16.h>
#include <cfloat>
#include <cstdint>

// ---------------------------------------------------------------------------
// GATv2 x3 + global max/mean pool + linear head.
// Round 13: REVERT round-12's cooperative mega-fusion (build_k had a serial
// bsum prefix chain + v[32] register spill -> 183 us @ 0.7% VALU; dispatch-
// overhead theory falsified). Back to round-11 separate kernels, keeping the
// 8-edge unrolled fused_agg (more gathers in flight).
// ---------------------------------------------------------------------------

typedef __attribute__((ext_vector_type(8))) short bf16x8;
typedef __attribute__((ext_vector_type(4))) float f32x4;
typedef __attribute__((ext_vector_type(2))) float v2f;
typedef __attribute__((ext_vector_type(4))) unsigned short us4;
typedef __attribute__((ext_vector_type(2))) unsigned short us2;

#define L2E 1.4426950408889634f

__device__ __forceinline__ float bf2f(unsigned short u) {
    return __uint_as_float((unsigned)u << 16);
}
__device__ __forceinline__ unsigned short f2bf(float f) {   // RNE
    unsigned u = __float_as_uint(f);
    u += 0x7FFFu + ((u >> 16) & 1u);
    return (unsigned short)(u >> 16);
}
__device__ __forceinline__ v2f unpack2(unsigned d) {        // [lo,hi] bf16 -> f32
    v2f r;
    r.x = __uint_as_float(d << 16);
    r.y = __uint_as_float(d & 0xffff0000u);
    return r;
}
__device__ __forceinline__ unsigned pack2(float a, float b) {
    return (unsigned)f2bf(a) | ((unsigned)f2bf(b) << 16);
}

// ---- cross-lane sum helpers -------------------------------------------------
template<int CTRL>
__device__ __forceinline__ float dpp_add_f(float x) {
    int xi = __float_as_int(x);
    int yi = __builtin_amdgcn_update_dpp(xi, xi, CTRL, 0xF, 0xF, false);
    return x + __int_as_float(yi);
}
template<int PAT>
__device__ __forceinline__ float swz_add_f(float x) {
    int yi = __builtin_amdgcn_ds_swizzle(__float_as_int(x), PAT);
    return x + __int_as_float(yi);
}
template<int GS>
__device__ __forceinline__ float group_sum(float p) {
    p = dpp_add_f<0x121>(p);   // row_ror:1
    p = dpp_add_f<0x122>(p);   // row_ror:2
    p = dpp_add_f<0x124>(p);   // row_ror:4
    p = dpp_add_f<0x128>(p);   // row_ror:8
    if constexpr (GS >= 32) p = swz_add_f<0x401F>(p);   // xor 16
    if constexpr (GS >= 64) p += __shfl_xor(p, 32, 64); // cross-half
    return p;
}

// ---------------------------------------------------------------------------
// init: deg=0, gsum=0, gcnt=0, gmaxu=enc(-FLT_MAX)
// ---------------------------------------------------------------------------
__global__ void init_k(int* __restrict__ deg, float* __restrict__ gsum,
                       float* __restrict__ gcnt, unsigned* __restrict__ gmaxu,
                       int N, int G)
{
    int i = blockIdx.x * blockDim.x + threadIdx.x;
    int stride = gridDim.x * blockDim.x;
    for (int k = i; k < N; k += stride) deg[k] = 0;
    for (int k = i; k < G * 64; k += stride) { gsum[k] = 0.f; gmaxu[k] = 0x00800000u; }
    for (int k = i; k < G; k += stride) gcnt[k] = 0.f;
}

// ---------------------------------------------------------------------------
// prep: x->bf16, 6 weights->bf16, dst histogram (deg zeroed by init_k).
// ---------------------------------------------------------------------------
__global__ void prep_k(const float* __restrict__ x, unsigned short* __restrict__ xb, int nx,
                       const float* p0, const float* p1, const float* p2,
                       const float* p3, const float* p4, const float* p5,
                       unsigned short* d0, unsigned short* d1, unsigned short* d2,
                       unsigned short* d3, unsigned short* d4, unsigned short* d5,
                       int s01, int s23, int s45,
                       const int* __restrict__ dste, int E, int N, int* __restrict__ deg)
{
    const int tid = blockIdx.x * blockDim.x + threadIdx.x;
    const int stride = gridDim.x * blockDim.x;

    for (int i = tid; i < nx / 4; i += stride) {
        int idx = i * 4;
        float4 v = *(const float4*)(x + idx);
        uint2 o = { pack2(v.x, v.y), pack2(v.z, v.w) };
        *(uint2*)(xb + idx) = o;
    }
    const int wtot4 = (2 * s01 + 2 * s23 + 2 * s45) / 4;
    const int t0 = 2 * s01, t1 = t0 + 2 * s23;
    for (int i = tid; i < wtot4; i += stride) {
        int e = i * 4;
        const float* s; unsigned short* d; int off;
        if (e < t0)      { int j = e;      s = (j < s01) ? p0 : p1; d = (j < s01) ? d0 : d1; off = j % s01; }
        else if (e < t1) { int j = e - t0; s = (j < s23) ? p2 : p3; d = (j < s23) ? d2 : d3; off = j % s23; }
        else             { int j = e - t1; s = (j < s45) ? p4 : p5; d = (j < s45) ? d4 : d5; off = j % s45; }
        float4 v = *(const float4*)(s + off);
        uint2 o = { pack2(v.x, v.y), pack2(v.z, v.w) };
        *(uint2*)(d + off) = o;
    }
    for (int e = tid; e < E + N; e += stride) {
        int i = (e < E) ? dste[e] : (e - E);
        atomicAdd(&deg[i], 1);
    }
}

// ---------------------------------------------------------------------------
// LDS-staged bf16 MFMA GEMM (round-10/11, unchanged).
// ---------------------------------------------------------------------------
template<int K, int SLAB>
__global__ __launch_bounds__(256) void gemm_lds(
    const unsigned short* __restrict__ A,
    const unsigned short* __restrict__ Wl, const unsigned short* __restrict__ Wr,
    unsigned short* __restrict__ Cl, unsigned short* __restrict__ Cr,
    int M, int Nout)
{
    constexpr int KC   = 128;
    constexpr int WPAD = KC + 8;
    constexpr int NT   = SLAB / 32;
    __shared__ unsigned short Ws[SLAB * WPAD];

    const int tid = threadIdx.x, wv = tid >> 6, lane = tid & 63;
    const int r16 = lane & 15, quad = lane >> 4;
    const int m0 = blockIdx.x * 64;
    const int mh = (wv >> 1) * 32;
    const int nh = (wv & 1) * (SLAB / 2);
    const int ncol0 = blockIdx.y * SLAB;

    f32x4 acc[2][2][NT] = {};

    const unsigned short* Arow[2];
    #pragma unroll
    for (int mt = 0; mt < 2; ++mt) {
        int r = m0 + mh + mt * 16 + r16;
        r = (r < M) ? r : (M - 1);
        Arow[mt] = A + (size_t)r * K + quad * 8;
    }

    for (int kc = 0; kc < K / KC; ++kc) {
        const int k0 = kc * KC;
        bf16x8 a[2][4];
        #pragma unroll
        for (int mt = 0; mt < 2; ++mt)
            #pragma unroll
            for (int ks = 0; ks < 4; ++ks)
                a[mt][ks] = *(const bf16x8*)(Arow[mt] + k0 + ks * 32);

        #pragma unroll
        for (int side = 0; side < 2; ++side) {
            const unsigned short* W = side ? Wr : Wl;
            __syncthreads();
            #pragma unroll
            for (int it = 0; it < SLAB * KC / 2048; ++it) {
                int idx8 = (it * 256 + tid) * 8;
                int row = idx8 >> 7, col = idx8 & 127;
                bf16x8 v = *(const bf16x8*)(W + (size_t)(ncol0 + row) * K + k0 + col);
                *(bf16x8*)(&Ws[row * WPAD + col]) = v;
            }
            __syncthreads();
            #pragma unroll
            for (int ks = 0; ks < 4; ++ks) {
                #pragma unroll
                for (int n = 0; n < NT; ++n) {
                    bf16x8 b = *(const bf16x8*)(&Ws[(nh + n * 16 + r16) * WPAD + ks * 32 + quad * 8]);
                    #pragma unroll
                    for (int mt = 0; mt < 2; ++mt)
                        acc[side][mt][n] = __builtin_amdgcn_mfma_f32_16x16x32_bf16(
                            a[mt][ks], b, acc[side][mt][n], 0, 0, 0);
                }
            }
        }
    }

    constexpr int RP  = SLAB / 2 + 8;
    constexpr int LPR = SLAB / 16;
    constexpr int RPI = 64 / LPR;
    const int il = lane % LPR, rr = lane / LPR;
    #pragma unroll
    for (int side = 0; side < 2; ++side) {
        unsigned short* C = side ? Cr : Cl;
        __syncthreads();
        unsigned short* L = &Ws[wv * 32 * RP];
        #pragma unroll
        for (int mt = 0; mt < 2; ++mt)
            #pragma unroll
            for (int n = 0; n < NT; ++n)
                #pragma unroll
                for (int r = 0; r < 4; ++r)
                    L[(mt * 16 + quad * 4 + r) * RP + n * 16 + r16] = f2bf(acc[side][mt][n][r]);
        #pragma unroll
        for (int t = 0; t < 32 / RPI; ++t) {
            int row = t * RPI + rr;
            uint4 v = *(const uint4*)(&L[row * RP + il * 8]);
            int gr = m0 + mh + row;
            if (gr < M)
                *(uint4*)(C + (size_t)gr * Nout + ncol0 + nh + il * 8) = v;
        }
    }
}

// ---------------------------------------------------------------------------
// 3-phase parallel scan (round-11 versions, no spill: 8 elems/thread)
// ---------------------------------------------------------------------------
__global__ __launch_bounds__(1024) void scanA_k(const int* __restrict__ deg,
                                                int* __restrict__ rowptr,
                                                int* __restrict__ bsum, int N)
{
    __shared__ int parts[16];
    const int t = threadIdx.x, lane = t & 63, wv = t >> 6;
    const int base = blockIdx.x * 8192;
    int v[8];
    int run = 0;
    #pragma unroll
    for (int i = 0; i < 8; ++i) {
        int idx = base + t * 8 + i;
        run += (idx < N) ? deg[idx] : 0;
        v[i] = run;
    }
    int x = run;
    #pragma unroll
    for (int off = 1; off < 64; off <<= 1) {
        int y = __shfl_up(x, off, 64);
        if (lane >= off) x += y;
    }
    int excl = x - run;
    if (lane == 63) parts[wv] = x;
    __syncthreads();
    if (wv == 0 && lane < 16) {
        int p = parts[lane];
        int xx = p;
        #pragma unroll
        for (int off = 1; off < 16; off <<= 1) {
            int y = __shfl_up(xx, off, 64);
            if (lane >= off) xx += y;
        }
        parts[lane] = xx - p;   // exclusive
    }
    __syncthreads();
    int pre = parts[wv] + excl;
    #pragma unroll
    for (int i = 0; i < 8; ++i) {
        int idx = base + t * 8 + i;
        if (idx < N) rowptr[idx + 1] = pre + v[i];
    }
    if (t == 1023) bsum[blockIdx.x] = parts[15] + x;   // block total
}

__global__ void scanB_k(int* __restrict__ bsum, int B)
{
    int lane = threadIdx.x;
    int v = (lane < B) ? bsum[lane] : 0;
    int x = v;
    #pragma unroll
    for (int off = 1; off < 64; off <<= 1) {
        int y = __shfl_up(x, off, 64);
        if (lane >= off) x += y;
    }
    if (lane < B) bsum[lane] = x - v;   // exclusive
}

__global__ __launch_bounds__(1024) void scanC_k(int* __restrict__ rowptr,
                                                const int* __restrict__ bsum, int N)
{
    const int b = blockIdx.x, t = threadIdx.x;
    if (b == 0) { if (t == 0) rowptr[0] = 0; return; }
    const int off = bsum[b];
    const int base = b * 8192;
    #pragma unroll
    for (int i = 0; i < 8; ++i) {
        int idx = base + t * 8 + i;
        if (idx < N) rowptr[idx + 1] += off;
    }
}

// scatter consumes deg (atomic countdown) -> no cursor buffer
__global__ void scatter_k(const int* __restrict__ src, const int* __restrict__ dst,
                          int E, int N, const int* __restrict__ rowptr,
                          int* __restrict__ deg, int* __restrict__ esrc)
{
    int e = blockIdx.x * blockDim.x + threadIdx.x;
    if (e >= E + N) return;
    int i = (e < E) ? dst[e] : (e - E);
    int j = (e < E) ? src[e] : (e - E);
    int old = atomicAdd(&deg[i], -1);
    esrc[rowptr[i] + old - 1] = j;
}

// ---------------------------------------------------------------------------
// Fused GATv2 layer: U-edge generic processor, 8/4/1 unroll ladder.
// ---------------------------------------------------------------------------
template<int P>
__device__ __forceinline__ float edge_logit(const v2f* xv, const v2f* xrv, const v2f* attv)
{
    v2f d = {0.f, 0.f};
    #pragma unroll
    for (int p = 0; p < P; ++p) {
        v2f z = xv[p] + xrv[p];
        v2f l = __builtin_elementwise_max(z, z * 0.2f);
        d += l * attv[p];
    }
    return d.x + d.y;
}

template<int P>
__device__ __forceinline__ void load_edge(const unsigned short* __restrict__ xl,
                                          size_t base, v2f* xv)
{
    if constexpr (P == 2) {
        uint2 a = *(const uint2*)(xl + base);
        xv[0] = unpack2(a.x); xv[1] = unpack2(a.y);
    } else {
        unsigned a = *(const unsigned*)(xl + base);
        xv[0] = unpack2(a);
    }
}

template<int U, int H>
__device__ __forceinline__ void do_edges(
    const unsigned short* __restrict__ xl, const int* __restrict__ esrc,
    int k, int f0, const v2f* xrv, const v2f* attv, float& s, v2f* acc)
{
    constexpr int P  = H / 2;
    constexpr int HD = H * 64;
    constexpr int GS = 64 / H;
    int j[U];
    #pragma unroll
    for (int i = 0; i < U; ++i) j[i] = esrc[k + i];
    v2f xv[U][P];
    #pragma unroll
    for (int i = 0; i < U; ++i)
        load_edge<P>(xl, (size_t)j[i] * HD + f0, xv[i]);
    float pl[U];
    #pragma unroll
    for (int i = 0; i < U; ++i) pl[i] = edge_logit<P>(xv[i], xrv, attv);
    #pragma unroll
    for (int i = 0; i < U; ++i) pl[i] = group_sum<GS>(pl[i]);
    float w[U];
    #pragma unroll
    for (int i = 0; i < U; ++i) w[i] = __builtin_amdgcn_exp2f(pl[i]);
    #pragma unroll
    for (int i = 0; i < U; ++i) s += w[i];
    #pragma unroll
    for (int p = 0; p < P; ++p) {
        v2f t = {0.f, 0.f};
        #pragma unroll
        for (int i = 0; i < U; ++i) t += xv[i][p] * w[i];
        acc[p] += t;
    }
}

template<int H, bool BF16OUT>
__global__ __launch_bounds__(256) void fused_agg_k(
    const unsigned short* __restrict__ xl, const unsigned short* __restrict__ xr,
    const int* __restrict__ rowptr, const int* __restrict__ esrc,
    const float* __restrict__ att, const float* __restrict__ bias,
    void* __restrict__ outv, int N, float oslope)
{
    const int wid  = __builtin_amdgcn_readfirstlane(
                         (blockIdx.x * blockDim.x + threadIdx.x) >> 6);
    const int lane = threadIdx.x & 63;
    if (wid >= N) return;
    constexpr int HD = H * 64;
    const int f0 = lane * H;
    const int r0 = rowptr[wid];
    const int r1 = rowptr[wid + 1];

    if constexpr (H >= 2) {
        constexpr int P = H / 2;
        v2f xrv[P], attv[P], acc[P];
        load_edge<P>(xr, (size_t)wid * HD + f0, xrv);
        #pragma unroll
        for (int p = 0; p < P; ++p) {
            attv[p] = *(const v2f*)(att + f0 + 2 * p) * L2E;
            acc[p] = (v2f){0.f, 0.f};
        }

        float s = 0.f;
        int k = r0;
        for (; k + 8 <= r1; k += 8) do_edges<8, H>(xl, esrc, k, f0, xrv, attv, s, acc);
        for (; k + 4 <= r1; k += 4) do_edges<4, H>(xl, esrc, k, f0, xrv, attv, s, acc);
        for (; k < r1; ++k)         do_edges<1, H>(xl, esrc, k, f0, xrv, attv, s, acc);

        float rs = 1.f / (s + 1e-16f);
        unsigned short o[H];
        float of[H];
        #pragma unroll
        for (int p = 0; p < P; ++p) {
            v2f b2 = *(const v2f*)(bias + f0 + 2 * p);
            v2f v = acc[p] * rs + b2;
            v = __builtin_elementwise_max(v, v * oslope);
            if constexpr (BF16OUT) { o[2 * p] = f2bf(v.x); o[2 * p + 1] = f2bf(v.y); }
            else                   { of[2 * p] = v.x; of[2 * p + 1] = v.y; }
        }
        if constexpr (BF16OUT) {
            unsigned short* ou = (unsigned short*)outv;
            if constexpr (H == 4) *(us4*)(ou + (size_t)wid * HD + f0) = *(us4*)o;
            else                  *(us2*)(ou + (size_t)wid * HD + f0) = *(us2*)o;
        } else {
            float* off_ = (float*)outv;
            #pragma unroll
            for (int i = 0; i < H; ++i) off_[(size_t)wid * HD + f0 + i] = of[i];
        }
    } else {
        // H == 1: scalar feats, GS = 64
        float xrv  = bf2f(xr[(size_t)wid * 64 + lane]);
        float attv = att[lane] * L2E;
        float s = 0.f, acc = 0.f;
        int k = r0;
        for (; k + 4 <= r1; k += 4) {
            int j[4];
            #pragma unroll
            for (int i = 0; i < 4; ++i) j[i] = esrc[k + i];
            float xv[4], pl[4], w[4];
            #pragma unroll
            for (int i = 0; i < 4; ++i) xv[i] = bf2f(xl[(size_t)j[i] * 64 + lane]);
            #pragma unroll
            for (int i = 0; i < 4; ++i) {
                float z = xv[i] + xrv;
                pl[i] = fmaxf(z, 0.2f * z) * attv;
            }
            #pragma unroll
            for (int i = 0; i < 4; ++i) pl[i] = group_sum<64>(pl[i]);
            #pragma unroll
            for (int i = 0; i < 4; ++i) w[i] = __builtin_amdgcn_exp2f(pl[i]);
            s += (w[0] + w[1]) + (w[2] + w[3]);
            acc += (xv[0] * w[0] + xv[1] * w[1]) + (xv[2] * w[2] + xv[3] * w[3]);
        }
        for (; k < r1; ++k) {
            float x0 = bf2f(xl[(size_t)esrc[k] * 64 + lane]);
            float z = x0 + xrv;
            float pl = group_sum<64>(fmaxf(z, 0.2f * z) * attv);
            float w = __builtin_amdgcn_exp2f(pl);
            s += w;
            acc += x0 * w;
        }
        float rs = 1.f / (s + 1e-16f);
        float v = acc * rs + bias[lane];
        v = fmaxf(v, oslope * v);
        if constexpr (BF16OUT)
            ((unsigned short*)outv)[(size_t)wid * 64 + lane] = f2bf(v);
        else
            ((float*)outv)[(size_t)wid * 64 + lane] = v;
    }
}

// ---------------------------------------------------------------------------
// Pooling (batch_index sorted -> run aggregation, atomics at boundaries only)
// ---------------------------------------------------------------------------
__device__ __forceinline__ unsigned fenc(float f) {
    unsigned u = __float_as_uint(f);
    return (u & 0x80000000u) ? ~u : (u | 0x80000000u);
}
__device__ __forceinline__ float fdec(unsigned u) {
    return __uint_as_float((u & 0x80000000u) ? (u & 0x7fffffffu) : ~u);
}

__global__ __launch_bounds__(256) void pool_k(
    const float* __restrict__ h, const int* __restrict__ batch, int N,
    unsigned* __restrict__ gmaxu, float* __restrict__ gsum, float* __restrict__ gcnt)
{
    const int wid  = (blockIdx.x * blockDim.x + threadIdx.x) >> 6;
    const int lane = threadIdx.x & 63;
    const int n0 = wid * 16;
    if (n0 >= N) return;
    int gcur = batch[n0];
    float vmax = -3.4e38f, vsum = 0.f;
    int cnt = 0;
    #pragma unroll 4
    for (int i = 0; i < 16; ++i) {
        int n = n0 + i;
        if (n >= N) break;
        int g = batch[n];
        if (g != gcur) {
            atomicMax(&gmaxu[gcur * 64 + lane], fenc(vmax));
            atomicAdd(&gsum[gcur * 64 + lane], vsum);
            if (lane == 0) atomicAdd(&gcnt[gcur], (float)cnt);
            gcur = g; vmax = -3.4e38f; vsum = 0.f; cnt = 0;
        }
        float v = h[(size_t)n * 64 + lane];
        vmax = fmaxf(vmax, v);
        vsum += v;
        cnt++;
    }
    atomicMax(&gmaxu[gcur * 64 + lane], fenc(vmax));
    atomicAdd(&gsum[gcur * 64 + lane], vsum);
    if (lane == 0) atomicAdd(&gcnt[gcur], (float)cnt);
}

__global__ __launch_bounds__(128) void final_k(
    const unsigned* __restrict__ gmaxu, const float* __restrict__ gsum,
    const float* __restrict__ gcnt, const float* __restrict__ out_w,
    const float* __restrict__ out_b, float* __restrict__ out,
    float* __restrict__ hid_out)
{
    const int g = blockIdx.x;
    const int t = threadIdx.x;
    __shared__ float hid[128];
    float v;
    if (t < 64) {
        v = fdec(gmaxu[g * 64 + t]);
    } else {
        float c = fmaxf(gcnt[g], 1.f);
        v = gsum[g * 64 + (t - 64)] / c;
    }
    hid[t] = v;
    hid_out[(size_t)g * 128 + t] = v;
    __syncthreads();
    const int w = t >> 6, lane = t & 63;
    float p = hid[lane] * out_w[w * 128 + lane] + hid[lane + 64] * out_w[w * 128 + 64 + lane];
    #pragma unroll
    for (int off = 32; off >= 1; off >>= 1) p += __shfl_xor(p, off, 64);
    if (lane == 0) out[g * 2 + w] = p + out_b[w];
}

// ---------------------------------------------------------------------------
extern "C" void kernel_launch(void* const* d_in, const int* in_sizes, int n_in,
                              void* d_out, int out_size, void* d_ws, size_t ws_size,
                              hipStream_t stream)
{
    const float* x    = (const float*)d_in[0];
    const int*   ei   = (const int*)d_in[1];
    const int*   batch= (const int*)d_in[2];
    const float* w1l  = (const float*)d_in[3];
    const float* w1r  = (const float*)d_in[4];
    const float* att1 = (const float*)d_in[5];
    const float* b1   = (const float*)d_in[6];
    const float* w2l  = (const float*)d_in[7];
    const float* w2r  = (const float*)d_in[8];
    const float* att2 = (const float*)d_in[9];
    const float* b2   = (const float*)d_in[10];
    const float* w3l  = (const float*)d_in[11];
    const float* w3r  = (const float*)d_in[12];
    const float* att3 = (const float*)d_in[13];
    const float* b3   = (const float*)d_in[14];
    const float* outw = (const float*)d_in[15];
    const float* outb = (const float*)d_in[16];

    const int N   = in_sizes[2];
    const int E   = in_sizes[1] / 2;
    const int E2  = E + N;
    const int G   = 256;
    const int FIN = in_sizes[0] / N;    // 128
    const int* src = ei;
    const int* dst = ei + E;

    char* ws = (char*)d_ws;
    size_t off = 0;
    auto alloc = [&](size_t bytes) -> void* {
        void* p = ws + off;
        off = (off + bytes + 255) & ~(size_t)255;
        return p;
    };
    unsigned short* xlb   = (unsigned short*)alloc((size_t)N * 256 * 2);
    unsigned short* xrb   = (unsigned short*)alloc((size_t)N * 256 * 2);
    unsigned short* xb    = (unsigned short*)alloc((size_t)N * 128 * 2);
    unsigned short* hAb   = (unsigned short*)alloc((size_t)N * 256 * 2);
    unsigned short* hBb   = (unsigned short*)alloc((size_t)N * 128 * 2);
    float*          h3    = (float*)alloc((size_t)N * 64 * 4);
    int*            rowptr= (int*)alloc((size_t)(N + 1) * 4);
    int*            deg   = (int*)alloc((size_t)N * 4);
    int*            esrc  = (int*)alloc((size_t)E2 * 4);
    int*            bsum  = (int*)alloc(64 * 4);
    unsigned*       gmaxu = (unsigned*)alloc((size_t)G * 64 * 4);
    float*          gsum  = (float*)alloc((size_t)G * 64 * 4);
    float*          gcnt  = (float*)alloc((size_t)G * 4);
    unsigned short* w1lb  = (unsigned short*)alloc(256 * 128 * 2);
    unsigned short* w1rb  = (unsigned short*)alloc(256 * 128 * 2);
    unsigned short* w2lb  = (unsigned short*)alloc(128 * 256 * 2);
    unsigned short* w2rb  = (unsigned short*)alloc(128 * 256 * 2);
    unsigned short* w3lb  = (unsigned short*)alloc(64 * 128 * 2);
    unsigned short* w3rb  = (unsigned short*)alloc(64 * 128 * 2);

    init_k<<<(N + 255) / 256, 256, 0, stream>>>(deg, gsum, gcnt, gmaxu, N, G);

    const int s1 = 256 * 128, s2 = 128 * 256, s3 = 64 * 128;
    prep_k<<<1024, 256, 0, stream>>>(x, xb, N * FIN,
        w1l, w1r, w2l, w2r, w3l, w3r, w1lb, w1rb, w2lb, w2rb, w3lb, w3rb,
        s1, s2, s3, dst, E, N, deg);

    // CSR: 3-phase scan + scatter
    const int nblk = (N + 8191) / 8192;
    scanA_k<<<nblk, 1024, 0, stream>>>(deg, rowptr, bsum, N);
    scanB_k<<<1, 64, 0, stream>>>(bsum, nblk);
    scanC_k<<<nblk, 1024, 0, stream>>>(rowptr, bsum, N);
    scatter_k<<<(E2 + 255) / 256, 256, 0, stream>>>(src, dst, E, N, rowptr, deg, esrc);

    const int gx  = (N + 63) / 64;           // 64-row GEMM blocks
    const int nwb = (N * 64 + 255) / 256;    // one wave per node

    // ---- layer 1: K=128 -> H=4, HD=256 (SLAB=128, 2 col-blocks)
    gemm_lds<128, 128><<<dim3(gx, 2), 256, 0, stream>>>(
        xb, w1lb, w1rb, xlb, xrb, N, 256);
    fused_agg_k<4, true><<<nwb, 256, 0, stream>>>(xlb, xrb, rowptr, esrc, att1, b1, hAb, N, 0.01f);

    // ---- layer 2: K=256 -> H=2, HD=128 (SLAB=128)
    gemm_lds<256, 128><<<dim3(gx, 1), 256, 0, stream>>>(
        hAb, w2lb, w2rb, xlb, xrb, N, 128);
    fused_agg_k<2, true><<<nwb, 256, 0, stream>>>(xlb, xrb, rowptr, esrc, att2, b2, hBb, N, 0.01f);

    // ---- layer 3: K=128 -> H=1, HD=64 (SLAB=64)
    gemm_lds<128, 64><<<dim3(gx, 1), 256, 0, stream>>>(
        hBb, w3lb, w3rb, xlb, xrb, N, 64);
    fused_agg_k<1, false><<<nwb, 256, 0, stream>>>(xlb, xrb, rowptr, esrc, att3, b3, h3, N, 0.01f);

    // ---- pooling + head
    const int pb = (N / 16 + 3) / 4;
    pool_k<<<pb, 256, 0, stream>>>(h3, batch, N, gmaxu, gsum, gcnt);
    final_k<<<G, 128, 0, stream>>>(gmaxu, gsum, gcnt, outw, outb,
                                   (float*)d_out, (float*)d_out + G * 2);
}

// Round 14
// 331.313 us; speedup vs baseline: 1.6566x; 1.0197x over previous
//
#include <hip/hip_runtime.h>
#include <hip/hip_bf16.h>
#include <cfloat>
#include <cstdint>

// ---------------------------------------------------------------------------
// GATv2 x3 + global max/mean pool + linear head.
// Round 14: fused_agg reverted to the measured-best inline 4-edge unroll
// (round-13's 8-edge ladder: VGPR 32->48, occupancy 58->39%, 44->49.6 us —
// TLP beats ILP in this kernel). h3 carried bf16 so pool reads half the bytes.
// ---------------------------------------------------------------------------

typedef __attribute__((ext_vector_type(8))) short bf16x8;
typedef __attribute__((ext_vector_type(4))) float f32x4;
typedef __attribute__((ext_vector_type(2))) float v2f;
typedef __attribute__((ext_vector_type(4))) unsigned short us4;
typedef __attribute__((ext_vector_type(2))) unsigned short us2;

#define L2E 1.4426950408889634f

__device__ __forceinline__ float bf2f(unsigned short u) {
    return __uint_as_float((unsigned)u << 16);
}
__device__ __forceinline__ unsigned short f2bf(float f) {   // RNE
    unsigned u = __float_as_uint(f);
    u += 0x7FFFu + ((u >> 16) & 1u);
    return (unsigned short)(u >> 16);
}
__device__ __forceinline__ v2f unpack2(unsigned d) {        // [lo,hi] bf16 -> f32
    v2f r;
    r.x = __uint_as_float(d << 16);
    r.y = __uint_as_float(d & 0xffff0000u);
    return r;
}
__device__ __forceinline__ unsigned pack2(float a, float b) {
    return (unsigned)f2bf(a) | ((unsigned)f2bf(b) << 16);
}

// ---- cross-lane sum helpers -------------------------------------------------
template<int CTRL>
__device__ __forceinline__ float dpp_add_f(float x) {
    int xi = __float_as_int(x);
    int yi = __builtin_amdgcn_update_dpp(xi, xi, CTRL, 0xF, 0xF, false);
    return x + __int_as_float(yi);
}
template<int PAT>
__device__ __forceinline__ float swz_add_f(float x) {
    int yi = __builtin_amdgcn_ds_swizzle(__float_as_int(x), PAT);
    return x + __int_as_float(yi);
}
template<int GS>
__device__ __forceinline__ float group_sum(float p) {
    p = dpp_add_f<0x121>(p);   // row_ror:1
    p = dpp_add_f<0x122>(p);   // row_ror:2
    p = dpp_add_f<0x124>(p);   // row_ror:4
    p = dpp_add_f<0x128>(p);   // row_ror:8
    if constexpr (GS >= 32) p = swz_add_f<0x401F>(p);   // xor 16
    if constexpr (GS >= 64) p += __shfl_xor(p, 32, 64); // cross-half
    return p;
}

// ---------------------------------------------------------------------------
// init: deg=0, gsum=0, gcnt=0, gmaxu=enc(-FLT_MAX)
// ---------------------------------------------------------------------------
__global__ void init_k(int* __restrict__ deg, float* __restrict__ gsum,
                       float* __restrict__ gcnt, unsigned* __restrict__ gmaxu,
                       int N, int G)
{
    int i = blockIdx.x * blockDim.x + threadIdx.x;
    int stride = gridDim.x * blockDim.x;
    for (int k = i; k < N; k += stride) deg[k] = 0;
    for (int k = i; k < G * 64; k += stride) { gsum[k] = 0.f; gmaxu[k] = 0x00800000u; }
    for (int k = i; k < G; k += stride) gcnt[k] = 0.f;
}

// ---------------------------------------------------------------------------
// prep: x->bf16, 6 weights->bf16, dst histogram (deg zeroed by init_k).
// ---------------------------------------------------------------------------
__global__ void prep_k(const float* __restrict__ x, unsigned short* __restrict__ xb, int nx,
                       const float* p0, const float* p1, const float* p2,
                       const float* p3, const float* p4, const float* p5,
                       unsigned short* d0, unsigned short* d1, unsigned short* d2,
                       unsigned short* d3, unsigned short* d4, unsigned short* d5,
                       int s01, int s23, int s45,
                       const int* __restrict__ dste, int E, int N, int* __restrict__ deg)
{
    const int tid = blockIdx.x * blockDim.x + threadIdx.x;
    const int stride = gridDim.x * blockDim.x;

    for (int i = tid; i < nx / 4; i += stride) {
        int idx = i * 4;
        float4 v = *(const float4*)(x + idx);
        uint2 o = { pack2(v.x, v.y), pack2(v.z, v.w) };
        *(uint2*)(xb + idx) = o;
    }
    const int wtot4 = (2 * s01 + 2 * s23 + 2 * s45) / 4;
    const int t0 = 2 * s01, t1 = t0 + 2 * s23;
    for (int i = tid; i < wtot4; i += stride) {
        int e = i * 4;
        const float* s; unsigned short* d; int off;
        if (e < t0)      { int j = e;      s = (j < s01) ? p0 : p1; d = (j < s01) ? d0 : d1; off = j % s01; }
        else if (e < t1) { int j = e - t0; s = (j < s23) ? p2 : p3; d = (j < s23) ? d2 : d3; off = j % s23; }
        else             { int j = e - t1; s = (j < s45) ? p4 : p5; d = (j < s45) ? d4 : d5; off = j % s45; }
        float4 v = *(const float4*)(s + off);
        uint2 o = { pack2(v.x, v.y), pack2(v.z, v.w) };
        *(uint2*)(d + off) = o;
    }
    for (int e = tid; e < E + N; e += stride) {
        int i = (e < E) ? dste[e] : (e - E);
        atomicAdd(&deg[i], 1);
    }
}

// ---------------------------------------------------------------------------
// LDS-staged bf16 MFMA GEMM (round-10/11, unchanged).
// ---------------------------------------------------------------------------
template<int K, int SLAB>
__global__ __launch_bounds__(256) void gemm_lds(
    const unsigned short* __restrict__ A,
    const unsigned short* __restrict__ Wl, const unsigned short* __restrict__ Wr,
    unsigned short* __restrict__ Cl, unsigned short* __restrict__ Cr,
    int M, int Nout)
{
    constexpr int KC   = 128;
    constexpr int WPAD = KC + 8;
    constexpr int NT   = SLAB / 32;
    __shared__ unsigned short Ws[SLAB * WPAD];

    const int tid = threadIdx.x, wv = tid >> 6, lane = tid & 63;
    const int r16 = lane & 15, quad = lane >> 4;
    const int m0 = blockIdx.x * 64;
    const int mh = (wv >> 1) * 32;
    const int nh = (wv & 1) * (SLAB / 2);
    const int ncol0 = blockIdx.y * SLAB;

    f32x4 acc[2][2][NT] = {};

    const unsigned short* Arow[2];
    #pragma unroll
    for (int mt = 0; mt < 2; ++mt) {
        int r = m0 + mh + mt * 16 + r16;
        r = (r < M) ? r : (M - 1);
        Arow[mt] = A + (size_t)r * K + quad * 8;
    }

    for (int kc = 0; kc < K / KC; ++kc) {
        const int k0 = kc * KC;
        bf16x8 a[2][4];
        #pragma unroll
        for (int mt = 0; mt < 2; ++mt)
            #pragma unroll
            for (int ks = 0; ks < 4; ++ks)
                a[mt][ks] = *(const bf16x8*)(Arow[mt] + k0 + ks * 32);

        #pragma unroll
        for (int side = 0; side < 2; ++side) {
            const unsigned short* W = side ? Wr : Wl;
            __syncthreads();
            #pragma unroll
            for (int it = 0; it < SLAB * KC / 2048; ++it) {
                int idx8 = (it * 256 + tid) * 8;
                int row = idx8 >> 7, col = idx8 & 127;
                bf16x8 v = *(const bf16x8*)(W + (size_t)(ncol0 + row) * K + k0 + col);
                *(bf16x8*)(&Ws[row * WPAD + col]) = v;
            }
            __syncthreads();
            #pragma unroll
            for (int ks = 0; ks < 4; ++ks) {
                #pragma unroll
                for (int n = 0; n < NT; ++n) {
                    bf16x8 b = *(const bf16x8*)(&Ws[(nh + n * 16 + r16) * WPAD + ks * 32 + quad * 8]);
                    #pragma unroll
                    for (int mt = 0; mt < 2; ++mt)
                        acc[side][mt][n] = __builtin_amdgcn_mfma_f32_16x16x32_bf16(
                            a[mt][ks], b, acc[side][mt][n], 0, 0, 0);
                }
            }
        }
    }

    constexpr int RP  = SLAB / 2 + 8;
    constexpr int LPR = SLAB / 16;
    constexpr int RPI = 64 / LPR;
    const int il = lane % LPR, rr = lane / LPR;
    #pragma unroll
    for (int side = 0; side < 2; ++side) {
        unsigned short* C = side ? Cr : Cl;
        __syncthreads();
        unsigned short* L = &Ws[wv * 32 * RP];
        #pragma unroll
        for (int mt = 0; mt < 2; ++mt)
            #pragma unroll
            for (int n = 0; n < NT; ++n)
                #pragma unroll
                for (int r = 0; r < 4; ++r)
                    L[(mt * 16 + quad * 4 + r) * RP + n * 16 + r16] = f2bf(acc[side][mt][n][r]);
        #pragma unroll
        for (int t = 0; t < 32 / RPI; ++t) {
            int row = t * RPI + rr;
            uint4 v = *(const uint4*)(&L[row * RP + il * 8]);
            int gr = m0 + mh + row;
            if (gr < M)
                *(uint4*)(C + (size_t)gr * Nout + ncol0 + nh + il * 8) = v;
        }
    }
}

// ---------------------------------------------------------------------------
// 3-phase parallel scan
// ---------------------------------------------------------------------------
__global__ __launch_bounds__(1024) void scanA_k(const int* __restrict__ deg,
                                                int* __restrict__ rowptr,
                                                int* __restrict__ bsum, int N)
{
    __shared__ int parts[16];
    const int t = threadIdx.x, lane = t & 63, wv = t >> 6;
    const int base = blockIdx.x * 8192;
    int v[8];
    int run = 0;
    #pragma unroll
    for (int i = 0; i < 8; ++i) {
        int idx = base + t * 8 + i;
        run += (idx < N) ? deg[idx] : 0;
        v[i] = run;
    }
    int x = run;
    #pragma unroll
    for (int off = 1; off < 64; off <<= 1) {
        int y = __shfl_up(x, off, 64);
        if (lane >= off) x += y;
    }
    int excl = x - run;
    if (lane == 63) parts[wv] = x;
    __syncthreads();
    if (wv == 0 && lane < 16) {
        int p = parts[lane];
        int xx = p;
        #pragma unroll
        for (int off = 1; off < 16; off <<= 1) {
            int y = __shfl_up(xx, off, 64);
            if (lane >= off) xx += y;
        }
        parts[lane] = xx - p;   // exclusive
    }
    __syncthreads();
    int pre = parts[wv] + excl;
    #pragma unroll
    for (int i = 0; i < 8; ++i) {
        int idx = base + t * 8 + i;
        if (idx < N) rowptr[idx + 1] = pre + v[i];
    }
    if (t == 1023) bsum[blockIdx.x] = parts[15] + x;   // block total
}

__global__ void scanB_k(int* __restrict__ bsum, int B)
{
    int lane = threadIdx.x;
    int v = (lane < B) ? bsum[lane] : 0;
    int x = v;
    #pragma unroll
    for (int off = 1; off < 64; off <<= 1) {
        int y = __shfl_up(x, off, 64);
        if (lane >= off) x += y;
    }
    if (lane < B) bsum[lane] = x - v;   // exclusive
}

__global__ __launch_bounds__(1024) void scanC_k(int* __restrict__ rowptr,
                                                const int* __restrict__ bsum, int N)
{
    const int b = blockIdx.x, t = threadIdx.x;
    if (b == 0) { if (t == 0) rowptr[0] = 0; return; }
    const int off = bsum[b];
    const int base = b * 8192;
    #pragma unroll
    for (int i = 0; i < 8; ++i) {
        int idx = base + t * 8 + i;
        if (idx < N) rowptr[idx + 1] += off;
    }
}

// scatter consumes deg (atomic countdown) -> no cursor buffer
__global__ void scatter_k(const int* __restrict__ src, const int* __restrict__ dst,
                          int E, int N, const int* __restrict__ rowptr,
                          int* __restrict__ deg, int* __restrict__ esrc)
{
    int e = blockIdx.x * blockDim.x + threadIdx.x;
    if (e >= E + N) return;
    int i = (e < E) ? dst[e] : (e - E);
    int j = (e < E) ? src[e] : (e - E);
    int old = atomicAdd(&deg[i], -1);
    esrc[rowptr[i] + old - 1] = j;
}

// ---------------------------------------------------------------------------
// Fused GATv2 layer — measured-best form: inline 4-edge unroll, VGPR ~32,
// DPP reduce, max-form leaky, pre-scaled att (exp2), scalar wave index.
// ---------------------------------------------------------------------------
template<int P>
__device__ __forceinline__ float edge_logit(const v2f* xv, const v2f* xrv, const v2f* attv)
{
    v2f d = {0.f, 0.f};
    #pragma unroll
    for (int p = 0; p < P; ++p) {
        v2f z = xv[p] + xrv[p];
        v2f l = __builtin_elementwise_max(z, z * 0.2f);   // leaky = max(z, 0.2z)
        d += l * attv[p];
    }
    return d.x + d.y;
}

template<int P>
__device__ __forceinline__ void load_edge(const unsigned short* __restrict__ xl,
                                          size_t base, v2f* xv)
{
    if constexpr (P == 2) {
        uint2 a = *(const uint2*)(xl + base);
        xv[0] = unpack2(a.x); xv[1] = unpack2(a.y);
    } else {
        unsigned a = *(const unsigned*)(xl + base);
        xv[0] = unpack2(a);
    }
}

template<int H, bool BF16OUT>
__global__ __launch_bounds__(256) void fused_agg_k(
    const unsigned short* __restrict__ xl, const unsigned short* __restrict__ xr,
    const int* __restrict__ rowptr, const int* __restrict__ esrc,
    const float* __restrict__ att, const float* __restrict__ bias,
    void* __restrict__ outv, int N, float oslope)
{
    const int wid  = __builtin_amdgcn_readfirstlane(
                         (blockIdx.x * blockDim.x + threadIdx.x) >> 6);
    const int lane = threadIdx.x & 63;
    if (wid >= N) return;
    constexpr int HD = H * 64;
    constexpr int GS = 64 / H;
    const int f0 = lane * H;
    const int r0 = rowptr[wid];
    const int r1 = rowptr[wid + 1];

    if constexpr (H >= 2) {
        constexpr int P = H / 2;
        v2f xrv[P], attv[P], acc[P];
        load_edge<P>(xr, (size_t)wid * HD + f0, xrv);
        #pragma unroll
        for (int p = 0; p < P; ++p) {
            attv[p] = *(const v2f*)(att + f0 + 2 * p) * L2E;
            acc[p] = (v2f){0.f, 0.f};
        }

        float s = 0.f;
        int k = r0;
        for (; k + 4 <= r1; k += 4) {
            int j[4];
            #pragma unroll
            for (int i = 0; i < 4; ++i) j[i] = esrc[k + i];
            v2f xv[4][P];
            #pragma unroll
            for (int i = 0; i < 4; ++i)
                load_edge<P>(xl, (size_t)j[i] * HD + f0, xv[i]);
            float pl[4];
            #pragma unroll
            for (int i = 0; i < 4; ++i) pl[i] = edge_logit<P>(xv[i], xrv, attv);
            #pragma unroll
            for (int i = 0; i < 4; ++i) pl[i] = group_sum<GS>(pl[i]);
            float w[4];
            #pragma unroll
            for (int i = 0; i < 4; ++i) w[i] = __builtin_amdgcn_exp2f(pl[i]);
            s += (w[0] + w[1]) + (w[2] + w[3]);
            #pragma unroll
            for (int p = 0; p < P; ++p) {
                v2f t = xv[0][p] * w[0] + xv[1][p] * w[1];
                t += xv[2][p] * w[2] + xv[3][p] * w[3];
                acc[p] += t;
            }
        }
        for (; k < r1; ++k) {
            int j0 = esrc[k];
            v2f xv[P];
            load_edge<P>(xl, (size_t)j0 * HD + f0, xv);
            float pl = group_sum<GS>(edge_logit<P>(xv, xrv, attv));
            float w = __builtin_amdgcn_exp2f(pl);
            s += w;
            #pragma unroll
            for (int p = 0; p < P; ++p) acc[p] += xv[p] * w;
        }

        float rs = 1.f / (s + 1e-16f);
        unsigned short o[H];
        float of[H];
        #pragma unroll
        for (int p = 0; p < P; ++p) {
            v2f b2 = *(const v2f*)(bias + f0 + 2 * p);
            v2f v = acc[p] * rs + b2;
            v = __builtin_elementwise_max(v, v * oslope);
            if constexpr (BF16OUT) { o[2 * p] = f2bf(v.x); o[2 * p + 1] = f2bf(v.y); }
            else                   { of[2 * p] = v.x; of[2 * p + 1] = v.y; }
        }
        if constexpr (BF16OUT) {
            unsigned short* ou = (unsigned short*)outv;
            if constexpr (H == 4) *(us4*)(ou + (size_t)wid * HD + f0) = *(us4*)o;
            else                  *(us2*)(ou + (size_t)wid * HD + f0) = *(us2*)o;
        } else {
            float* off_ = (float*)outv;
            #pragma unroll
            for (int i = 0; i < H; ++i) off_[(size_t)wid * HD + f0 + i] = of[i];
        }
    } else {
        // H == 1: scalar feats, GS = 64
        float xrv  = bf2f(xr[(size_t)wid * 64 + lane]);
        float attv = att[lane] * L2E;
        float s = 0.f, acc = 0.f;
        int k = r0;
        for (; k + 4 <= r1; k += 4) {
            int j[4];
            #pragma unroll
            for (int i = 0; i < 4; ++i) j[i] = esrc[k + i];
            float xv[4], pl[4], w[4];
            #pragma unroll
            for (int i = 0; i < 4; ++i) xv[i] = bf2f(xl[(size_t)j[i] * 64 + lane]);
            #pragma unroll
            for (int i = 0; i < 4; ++i) {
                float z = xv[i] + xrv;
                pl[i] = fmaxf(z, 0.2f * z) * attv;
            }
            #pragma unroll
            for (int i = 0; i < 4; ++i) pl[i] = group_sum<64>(pl[i]);
            #pragma unroll
            for (int i = 0; i < 4; ++i) w[i] = __builtin_amdgcn_exp2f(pl[i]);
            s += (w[0] + w[1]) + (w[2] + w[3]);
            acc += (xv[0] * w[0] + xv[1] * w[1]) + (xv[2] * w[2] + xv[3] * w[3]);
        }
        for (; k < r1; ++k) {
            float x0 = bf2f(xl[(size_t)esrc[k] * 64 + lane]);
            float z = x0 + xrv;
            float pl = group_sum<64>(fmaxf(z, 0.2f * z) * attv);
            float w = __builtin_amdgcn_exp2f(pl);
            s += w;
            acc += x0 * w;
        }
        float rs = 1.f / (s + 1e-16f);
        float v = acc * rs + bias[lane];
        v = fmaxf(v, oslope * v);
        if constexpr (BF16OUT)
            ((unsigned short*)outv)[(size_t)wid * 64 + lane] = f2bf(v);
        else
            ((float*)outv)[(size_t)wid * 64 + lane] = v;
    }
}

// ---------------------------------------------------------------------------
// Pooling (batch_index sorted -> run aggregation, atomics at boundaries only)
// h is bf16 (written by fused_agg_k<1,true>).
// ---------------------------------------------------------------------------
__device__ __forceinline__ unsigned fenc(float f) {
    unsigned u = __float_as_uint(f);
    return (u & 0x80000000u) ? ~u : (u | 0x80000000u);
}
__device__ __forceinline__ float fdec(unsigned u) {
    return __uint_as_float((u & 0x80000000u) ? (u & 0x7fffffffu) : ~u);
}

__global__ __launch_bounds__(256) void pool_k(
    const unsigned short* __restrict__ h, const int* __restrict__ batch, int N,
    unsigned* __restrict__ gmaxu, float* __restrict__ gsum, float* __restrict__ gcnt)
{
    const int wid  = (blockIdx.x * blockDim.x + threadIdx.x) >> 6;
    const int lane = threadIdx.x & 63;
    const int n0 = wid * 16;
    if (n0 >= N) return;
    int gcur = batch[n0];
    float vmax = -3.4e38f, vsum = 0.f;
    int cnt = 0;
    #pragma unroll 4
    for (int i = 0; i < 16; ++i) {
        int n = n0 + i;
        if (n >= N) break;
        int g = batch[n];
        if (g != gcur) {
            atomicMax(&gmaxu[gcur * 64 + lane], fenc(vmax));
            atomicAdd(&gsum[gcur * 64 + lane], vsum);
            if (lane == 0) atomicAdd(&gcnt[gcur], (float)cnt);
            gcur = g; vmax = -3.4e38f; vsum = 0.f; cnt = 0;
        }
        float v = bf2f(h[(size_t)n * 64 + lane]);
        vmax = fmaxf(vmax, v);
        vsum += v;
        cnt++;
    }
    atomicMax(&gmaxu[gcur * 64 + lane], fenc(vmax));
    atomicAdd(&gsum[gcur * 64 + lane], vsum);
    if (lane == 0) atomicAdd(&gcnt[gcur], (float)cnt);
}

__global__ __launch_bounds__(128) void final_k(
    const unsigned* __restrict__ gmaxu, const float* __restrict__ gsum,
    const float* __restrict__ gcnt, const float* __restrict__ out_w,
    const float* __restrict__ out_b, float* __restrict__ out,
    float* __restrict__ hid_out)
{
    const int g = blockIdx.x;
    const int t = threadIdx.x;
    __shared__ float hid[128];
    float v;
    if (t < 64) {
        v = fdec(gmaxu[g * 64 + t]);
    } else {
        float c = fmaxf(gcnt[g], 1.f);
        v = gsum[g * 64 + (t - 64)] / c;
    }
    hid[t] = v;
    hid_out[(size_t)g * 128 + t] = v;
    __syncthreads();
    const int w = t >> 6, lane = t & 63;
    float p = hid[lane] * out_w[w * 128 + lane] + hid[lane + 64] * out_w[w * 128 + 64 + lane];
    #pragma unroll
    for (int off = 32; off >= 1; off >>= 1) p += __shfl_xor(p, off, 64);
    if (lane == 0) out[g * 2 + w] = p + out_b[w];
}

// ---------------------------------------------------------------------------
extern "C" void kernel_launch(void* const* d_in, const int* in_sizes, int n_in,
                              void* d_out, int out_size, void* d_ws, size_t ws_size,
                              hipStream_t stream)
{
    const float* x    = (const float*)d_in[0];
    const int*   ei   = (const int*)d_in[1];
    const int*   batch= (const int*)d_in[2];
    const float* w1l  = (const float*)d_in[3];
    const float* w1r  = (const float*)d_in[4];
    const float* att1 = (const float*)d_in[5];
    const float* b1   = (const float*)d_in[6];
    const float* w2l  = (const float*)d_in[7];
    const float* w2r  = (const float*)d_in[8];
    const float* att2 = (const float*)d_in[9];
    const float* b2   = (const float*)d_in[10];
    const float* w3l  = (const float*)d_in[11];
    const float* w3r  = (const float*)d_in[12];
    const float* att3 = (const float*)d_in[13];
    const float* b3   = (const float*)d_in[14];
    const float* outw = (const float*)d_in[15];
    const float* outb = (const float*)d_in[16];

    const int N   = in_sizes[2];
    const int E   = in_sizes[1] / 2;
    const int E2  = E + N;
    const int G   = 256;
    const int FIN = in_sizes[0] / N;    // 128
    const int* src = ei;
    const int* dst = ei + E;

    char* ws = (char*)d_ws;
    size_t off = 0;
    auto alloc = [&](size_t bytes) -> void* {
        void* p = ws + off;
        off = (off + bytes + 255) & ~(size_t)255;
        return p;
    };
    unsigned short* xlb   = (unsigned short*)alloc((size_t)N * 256 * 2);
    unsigned short* xrb   = (unsigned short*)alloc((size_t)N * 256 * 2);
    unsigned short* xb    = (unsigned short*)alloc((size_t)N * 128 * 2);
    unsigned short* hAb   = (unsigned short*)alloc((size_t)N * 256 * 2);
    unsigned short* hBb   = (unsigned short*)alloc((size_t)N * 128 * 2);
    unsigned short* h3b   = (unsigned short*)alloc((size_t)N * 64 * 2);
    int*            rowptr= (int*)alloc((size_t)(N + 1) * 4);
    int*            deg   = (int*)alloc((size_t)N * 4);
    int*            esrc  = (int*)alloc((size_t)E2 * 4);
    int*            bsum  = (int*)alloc(64 * 4);
    unsigned*       gmaxu = (unsigned*)alloc((size_t)G * 64 * 4);
    float*          gsum  = (float*)alloc((size_t)G * 64 * 4);
    float*          gcnt  = (float*)alloc((size_t)G * 4);
    unsigned short* w1lb  = (unsigned short*)alloc(256 * 128 * 2);
    unsigned short* w1rb  = (unsigned short*)alloc(256 * 128 * 2);
    unsigned short* w2lb  = (unsigned short*)alloc(128 * 256 * 2);
    unsigned short* w2rb  = (unsigned short*)alloc(128 * 256 * 2);
    unsigned short* w3lb  = (unsigned short*)alloc(64 * 128 * 2);
    unsigned short* w3rb  = (unsigned short*)alloc(64 * 128 * 2);

    init_k<<<(N + 255) / 256, 256, 0, stream>>>(deg, gsum, gcnt, gmaxu, N, G);

    const int s1 = 256 * 128, s2 = 128 * 256, s3 = 64 * 128;
    prep_k<<<1024, 256, 0, stream>>>(x, xb, N * FIN,
        w1l, w1r, w2l, w2r, w3l, w3r, w1lb, w1rb, w2lb, w2rb, w3lb, w3rb,
        s1, s2, s3, dst, E, N, deg);

    // CSR: 3-phase scan + scatter
    const int nblk = (N + 8191) / 8192;
    scanA_k<<<nblk, 1024, 0, stream>>>(deg, rowptr, bsum, N);
    scanB_k<<<1, 64, 0, stream>>>(bsum, nblk);
    scanC_k<<<nblk, 1024, 0, stream>>>(rowptr, bsum, N);
    scatter_k<<<(E2 + 255) / 256, 256, 0, stream>>>(src, dst, E, N, rowptr, deg, esrc);

    const int gx  = (N + 63) / 64;           // 64-row GEMM blocks
    const int nwb = (N * 64 + 255) / 256;    // one wave per node

    // ---- layer 1: K=128 -> H=4, HD=256 (SLAB=128, 2 col-blocks)
    gemm_lds<128, 128><<<dim3(gx, 2), 256, 0, stream>>>(
        xb, w1lb, w1rb, xlb, xrb, N, 256);
    fused_agg_k<4, true><<<nwb, 256, 0, stream>>>(xlb, xrb, rowptr, esrc, att1, b1, hAb, N, 0.01f);

    // ---- layer 2: K=256 -> H=2, HD=128 (SLAB=128)
    gemm_lds<256, 128><<<dim3(gx, 1), 256, 0, stream>>>(
        hAb, w2lb, w2rb, xlb, xrb, N, 128);
    fused_agg_k<2, true><<<nwb, 256, 0, stream>>>(xlb, xrb, rowptr, esrc, att2, b2, hBb, N, 0.01f);

    // ---- layer 3: K=128 -> H=1, HD=64 (SLAB=64); bf16 out for pool
    gemm_lds<128, 64><<<dim3(gx, 1), 256, 0, stream>>>(
        hBb, w3lb, w3rb, xlb, xrb, N, 64);
    fused_agg_k<1, true><<<nwb, 256, 0, stream>>>(xlb, xrb, rowptr, esrc, att3, b3, h3b, N, 0.01f);

    // ---- pooling + head
    const int pb = (N / 16 + 3) / 4;
    pool_k<<<pb, 256, 0, stream>>>(h3b, batch, N, gmaxu, gsum, gcnt);
    final_k<<<G, 128, 0, stream>>>(gmaxu, gsum, gcnt, outw, outb,
                                   (float*)d_out, (float*)d_out + G * 2);
}